// Round 5
// baseline (50.230 us; speedup 1.0000x reference)
//
#include <hip/hip_runtime.h>

// GeometryKernelAttention: nearest-neighbor multi-scale gather + weighted sum.
// B=1, NQ=20000, H=8, L=4, P=8, D=32, NUM_VALUE=19560.
// Output: (1, 20000, 256) f32, returned twice (concatenated in d_out).
//
// R2: head<->XCD affinity (blockIdx%8 == head); FETCH_SIZE hit the 50 MB ideal.
// R3: LDS (f,w) staging — neutral -> not front-end bound.
// R4: bf16 gather — SAME speed as f32 -> bound by random row-REQUEST rate
//     (~116 G lines/s), not bytes.
// R5: reduce random requests: stage levels 2+3 (rows 18400..19559, 145 KB f32
//     per head) in LDS as bf16 (74.2 KB). Samples j>=16 are statically L2/L3
//     -> served from LDS; L0/L1 gathered f32 direct (conv kernel dropped).
//     128 queries/block amortizes staging: 5.12M random lines ->
//     2.56M random + 1.46M streamed.

#define GKA_NQ       20000
#define GKA_H        8
#define GKA_NV       19560
#define GKA_L23BASE  18400
#define GKA_L23ROWS  1160
#define GKA_OUT_HALF 5120000   // 20000 * 256

static __device__ __forceinline__ unsigned short f2bf(float x) {
    unsigned u = __float_as_uint(x);
    unsigned r = 0x7FFFu + ((u >> 16) & 1u);   // round-to-nearest-even
    return (unsigned short)((u + r) >> 16);
}
static __device__ __forceinline__ float bf2f(unsigned short b) {
    return __uint_as_float(((unsigned)b) << 16);
}

__global__ __launch_bounds__(1024) void gka_kernel(
    const float* __restrict__ value,   // [NV, 8, 32] f32 (b=1)
    const float* __restrict__ sloc,    // [NQ, 8, 4, 8, 2]
    const float* __restrict__ awgt,    // [NQ, 8, 4, 8]
    float* __restrict__ out)           // [2, NQ, 256]
{
    // bf16 copy of this head's level-2+3 slice: [1160 rows][32 vals] = 74240 B
    __shared__ ushort vlds[GKA_L23ROWS * 32];

    const int tid   = threadIdx.x;
    const int h     = blockIdx.x & 7;      // head == XCD (round-robin dispatch)
    const int chunk = blockIdx.x >> 3;

    // ---- Stage levels 2+3 of this head into LDS (f32 -> bf16) ----
    {
        const float* src = value + (size_t)GKA_L23BASE * 256 + h * 32;
        for (int i = tid; i < GKA_L23ROWS * 8; i += 1024) {
            const int r = i >> 3, c = i & 7;           // row, float4-column
            const float4 f = *(const float4*)(src + (size_t)r * 256 + c * 4);
            ushort4 b;
            b.x = f2bf(f.x); b.y = f2bf(f.y); b.z = f2bf(f.z); b.w = f2bf(f.w);
            *(ushort4*)(vlds + i * 4) = b;             // == r*32 + c*4
        }
    }

    const int lane = tid & 63;
    const int wave = tid >> 6;             // 0..15
    const int qq   = lane >> 3;            // query within wave
    const int sub  = lane & 7;             // d-quad / sample owner
    const int qloc = wave * 8 + qq;        // 0..127
    const int q    = chunk * 128 + qloc;
    const bool alive = (q < GKA_NQ);       // uniform per wave (boundary % 8 == 0)

    // ---- Phase A: compute 4 (flat, w) pairs; lane sub owns samples 4*sub.. ----
    // Sample j's level = j>>3, so lane-level lvl = sub>>1; subs 0-3 -> L0/L1
    // (global gather), subs 4-7 -> L2/L3 (LDS).
    const int lvl = sub >> 1;
    const int Wi  = (lvl == 0) ? 160 : (lvl == 1) ? 80 : (lvl == 2) ? 40 : 20;
    const int Hi  = (lvl == 0) ? 92  : (lvl == 1) ? 46 : (lvl == 2) ? 23 : 12;
    const int ls  = (lvl == 0) ? 0   : (lvl == 1) ? 14720 : (lvl == 2) ? 18400 : 19320;
    const float Wf = (float)Wi;
    const float Hf = (float)Hi;

    int   fl[4];
    float wk[4];
    if (alive) {
        const int qh = q * GKA_H + h;
        const float4* lp = (const float4*)(sloc + (size_t)qh * 64 + sub * 8);
        const float4 xy0 = lp[0];
        const float4 xy1 = lp[1];
        const float4 w4  = *(const float4*)(awgt + (size_t)qh * 32 + sub * 4);
        const float xs[4] = {xy0.x, xy0.z, xy1.x, xy1.z};
        const float ys[4] = {xy0.y, xy0.w, xy1.y, xy1.w};
        const float ws[4] = {w4.x, w4.y, w4.z, w4.w};
        #pragma unroll
        for (int k = 0; k < 4; ++k) {
            const int col = (int)floorf(xs[k] * Wf);
            const int row = (int)floorf(ys[k] * Hf);
            const bool valid = (col >= 0) & (col < Wi) & (row >= 0) & (row < Hi);
            int f = ls + row * Wi + col;
            f = min(max(f, 0), GKA_NV - 1);
            if (sub >= 4)   // LDS row index (w==0 whenever the clamp fires)
                f = min(max(f, GKA_L23BASE), GKA_NV - 1) - GKA_L23BASE;
            fl[k] = f;
            wk[k] = valid ? ws[k] : 0.0f;
        }
    } else {
        #pragma unroll
        for (int k = 0; k < 4; ++k) { fl[k] = 0; wk[k] = 0.0f; }
    }

    __syncthreads();

    // ---- Phase B: 16 global f32 gathers (L0/L1) + 16 LDS bf16 reads (L2/L3) ----
    float4 acc = make_float4(0.f, 0.f, 0.f, 0.f);
    const int gbase = lane & 56;
    if (alive) {
        const float* vg = value + h * 32 + sub * 4;
        #pragma unroll
        for (int j = 0; j < 16; ++j) {
            const int   s = gbase | (j >> 2);
            const int   f = __shfl(fl[j & 3], s, 64);
            const float w = __shfl(wk[j & 3], s, 64);
            const float4 v = *(const float4*)(vg + (size_t)f * 256);
            acc.x = fmaf(w, v.x, acc.x);
            acc.y = fmaf(w, v.y, acc.y);
            acc.z = fmaf(w, v.z, acc.z);
            acc.w = fmaf(w, v.w, acc.w);
        }
        const ushort* vl = vlds + sub * 4;
        #pragma unroll
        for (int j = 16; j < 32; ++j) {
            const int   s = gbase | (j >> 2);
            const int   r = __shfl(fl[j & 3], s, 64);
            const float w = __shfl(wk[j & 3], s, 64);
            const ushort4 v = *(const ushort4*)(vl + r * 32);
            acc.x = fmaf(w, bf2f(v.x), acc.x);
            acc.y = fmaf(w, bf2f(v.y), acc.y);
            acc.z = fmaf(w, bf2f(v.z), acc.z);
            acc.w = fmaf(w, bf2f(v.w), acc.w);
        }

        float* o = out + (size_t)q * 256 + h * 32 + sub * 4;
        *(float4*)o = acc;
        *(float4*)(o + GKA_OUT_HALF) = acc;
    }
}

extern "C" void kernel_launch(void* const* d_in, const int* in_sizes, int n_in,
                              void* d_out, int out_size, void* d_ws, size_t ws_size,
                              hipStream_t stream) {
    const float* value = (const float*)d_in[0];
    const float* sloc  = (const float*)d_in[3];
    const float* awgt  = (const float*)d_in[4];
    float* out = (float*)d_out;

    // ceil(20000/128)=157 query-chunks x 8 heads; blockIdx%8 == head.
    dim3 grid(157 * GKA_H);
    gka_kernel<<<grid, 1024, 0, stream>>>(value, sloc, awgt, out);
}

// Round 6
// 47.394 us; speedup vs baseline: 1.0598x; 1.0598x over previous
//
#include <hip/hip_runtime.h>

// GeometryKernelAttention: nearest-neighbor multi-scale gather + weighted sum.
// B=1, NQ=20000, H=8, L=4, P=8, D=32, NUM_VALUE=19560.
// Output: (1, 20000, 256) f32, returned twice (concatenated in d_out).
//
// R2: head<->XCD affinity (blockIdx%8 == head); FETCH_SIZE at the 50 MB ideal.
// R3: fw-in-LDS — neutral -> not front-end bound.
// R4: bf16 gather — same speed -> bound by random line-REQUEST count, not bytes.
// R5: LDS L2+L3 (74 KB) — regression: 1.77x amortization + occupancy loss.
// R6: (a) forced MLP: explicit 8-load batches, 2-deep rotation (~16 loads in
//     flight per wave); (b) stage ONLY level 3 (240 rows, 19.2 KB bf16,
//     bank-spread stride): 240 streamed lines replace 512 random per block.

#define GKA_NQ       20000
#define GKA_H        8
#define GKA_NV       19560
#define GKA_L3BASE   19320
#define GKA_L3ROWS   240
#define GKA_L3STR    40        // shorts per staged row (80 B -> spread banks)
#define GKA_OUT_HALF 5120000   // 20000 * 256

static __device__ __forceinline__ unsigned short f2bf(float x) {
    unsigned u = __float_as_uint(x);
    unsigned r = 0x7FFFu + ((u >> 16) & 1u);   // round-to-nearest-even
    return (unsigned short)((u + r) >> 16);
}
static __device__ __forceinline__ float bf2f(unsigned short b) {
    return __uint_as_float(((unsigned)b) << 16);
}

__global__ __launch_bounds__(512) void gka_kernel(
    const float* __restrict__ value,   // [NV, 8, 32] f32 (b=1)
    const float* __restrict__ sloc,    // [NQ, 8, 4, 8, 2]
    const float* __restrict__ awgt,    // [NQ, 8, 4, 8]
    float* __restrict__ out)           // [2, NQ, 256]
{
    __shared__ uint2  fw[64][34];                    // (f,w) per query x sample
    __shared__ ushort vl3[GKA_L3ROWS * GKA_L3STR];   // level-3 slice, bf16

    const int tid   = threadIdx.x;
    const int h     = blockIdx.x & 7;      // head == XCD (round-robin dispatch)
    const int chunk = blockIdx.x >> 3;

    // ---- Stage level 3 of this head into LDS (240 rows x 32, f32 -> bf16) ----
    {
        const float* src = value + (size_t)GKA_L3BASE * 256 + h * 32;
        for (int i = tid; i < GKA_L3ROWS * 8; i += 512) {
            const int r = i >> 3, c = i & 7;
            const float4 f = *(const float4*)(src + (size_t)r * 256 + c * 4);
            ushort4 b;
            b.x = f2bf(f.x); b.y = f2bf(f.y); b.z = f2bf(f.z); b.w = f2bf(f.w);
            *(ushort4*)(vl3 + r * GKA_L3STR + c * 4) = b;
        }
    }

    const int lane = tid & 63;
    const int wave = tid >> 6;             // 0..7
    const int qq   = lane >> 3;
    const int sub  = lane & 7;
    const int qloc = wave * 8 + qq;        // 0..63
    const int q    = chunk * 64 + qloc;
    const bool alive = (q < GKA_NQ);       // wave-uniform (20000 % 8 == 0)

    // ---- Phase A: lane sub owns samples 4*sub..4*sub+3 (level = sub>>1) ----
    const int lvl = sub >> 1;
    const int Wi  = (lvl == 0) ? 160 : (lvl == 1) ? 80 : (lvl == 2) ? 40 : 20;
    const int Hi  = (lvl == 0) ? 92  : (lvl == 1) ? 46 : (lvl == 2) ? 23 : 12;
    const int ls  = (lvl == 0) ? 0   : (lvl == 1) ? 14720 : (lvl == 2) ? 18400 : 19320;
    const float Wf = (float)Wi;
    const float Hf = (float)Hi;

    if (alive) {
        const int qh = q * GKA_H + h;
        const float4* lp = (const float4*)(sloc + (size_t)qh * 64 + sub * 8);
        const float4 xy0 = lp[0];
        const float4 xy1 = lp[1];
        const float4 w4  = *(const float4*)(awgt + (size_t)qh * 32 + sub * 4);
        const float xs[4] = {xy0.x, xy0.z, xy1.x, xy1.z};
        const float ys[4] = {xy0.y, xy0.w, xy1.y, xy1.w};
        const float ws[4] = {w4.x, w4.y, w4.z, w4.w};
        #pragma unroll
        for (int k = 0; k < 4; ++k) {
            const int col = (int)floorf(xs[k] * Wf);
            const int row = (int)floorf(ys[k] * Hf);
            const bool valid = (col >= 0) & (col < Wi) & (row >= 0) & (row < Hi);
            int f = ls + row * Wi + col;
            f = min(max(f, 0), GKA_NV - 1);
            if (lvl == 3)   // LDS-relative row (w==0 whenever clamp fires)
                f = min(max(f, GKA_L3BASE), GKA_NV - 1) - GKA_L3BASE;
            fw[qloc][4 * sub + k] = make_uint2((unsigned)f,
                                               __float_as_uint(valid ? ws[k] : 0.0f));
        }
    } else {
        #pragma unroll
        for (int k = 0; k < 4; ++k)
            fw[qloc][4 * sub + k] = make_uint2(0u, 0u);
    }

    __syncthreads();

    // ---- Phase B: deep-pipelined gathers ----
    float4 acc = make_float4(0.f, 0.f, 0.f, 0.f);
    const float*  vg = value + h * 32 + sub * 4;
    const ushort* vl = vl3 + sub * 4;
    const uint4*  rowp = (const uint4*)(&fw[qloc][0]);  // 2 (f,w) pairs / uint4

    uint4 PA[4], PB[4];
    float4 VA[8], VB[8];

    // issue batch A: level 2 (j16..23)
    #pragma unroll
    for (int t = 0; t < 4; ++t) PA[t] = rowp[8 + t];
    #pragma unroll
    for (int t = 0; t < 4; ++t) {
        VA[2 * t]     = *(const float4*)(vg + (size_t)PA[t].x * 256);
        VA[2 * t + 1] = *(const float4*)(vg + (size_t)PA[t].z * 256);
    }

    // level 3 from LDS (j24..31) — overlaps batch A latency
    {
        uint4 PL[4];
        #pragma unroll
        for (int t = 0; t < 4; ++t) PL[t] = rowp[12 + t];
        #pragma unroll
        for (int t = 0; t < 4; ++t) {
            const ushort4 u0 = *(const ushort4*)(vl + PL[t].x * GKA_L3STR);
            const ushort4 u1 = *(const ushort4*)(vl + PL[t].z * GKA_L3STR);
            const float w0 = __uint_as_float(PL[t].y);
            const float w1 = __uint_as_float(PL[t].w);
            acc.x = fmaf(w0, bf2f(u0.x), acc.x); acc.x = fmaf(w1, bf2f(u1.x), acc.x);
            acc.y = fmaf(w0, bf2f(u0.y), acc.y); acc.y = fmaf(w1, bf2f(u1.y), acc.y);
            acc.z = fmaf(w0, bf2f(u0.z), acc.z); acc.z = fmaf(w1, bf2f(u1.z), acc.z);
            acc.w = fmaf(w0, bf2f(u0.w), acc.w); acc.w = fmaf(w1, bf2f(u1.w), acc.w);
        }
    }

    // issue batch B: level 1 (j8..15)
    #pragma unroll
    for (int t = 0; t < 4; ++t) PB[t] = rowp[4 + t];
    #pragma unroll
    for (int t = 0; t < 4; ++t) {
        VB[2 * t]     = *(const float4*)(vg + (size_t)PB[t].x * 256);
        VB[2 * t + 1] = *(const float4*)(vg + (size_t)PB[t].z * 256);
    }

    // consume batch A (level 2)
    #pragma unroll
    for (int t = 0; t < 4; ++t) {
        const float w0 = __uint_as_float(PA[t].y);
        const float w1 = __uint_as_float(PA[t].w);
        acc.x = fmaf(w0, VA[2*t].x, acc.x); acc.x = fmaf(w1, VA[2*t+1].x, acc.x);
        acc.y = fmaf(w0, VA[2*t].y, acc.y); acc.y = fmaf(w1, VA[2*t+1].y, acc.y);
        acc.z = fmaf(w0, VA[2*t].z, acc.z); acc.z = fmaf(w1, VA[2*t+1].z, acc.z);
        acc.w = fmaf(w0, VA[2*t].w, acc.w); acc.w = fmaf(w1, VA[2*t+1].w, acc.w);
    }

    // issue batch A2: level 0 (j0..7), reusing PA/VA
    #pragma unroll
    for (int t = 0; t < 4; ++t) PA[t] = rowp[t];
    #pragma unroll
    for (int t = 0; t < 4; ++t) {
        VA[2 * t]     = *(const float4*)(vg + (size_t)PA[t].x * 256);
        VA[2 * t + 1] = *(const float4*)(vg + (size_t)PA[t].z * 256);
    }

    // consume batch B (level 1)
    #pragma unroll
    for (int t = 0; t < 4; ++t) {
        const float w0 = __uint_as_float(PB[t].y);
        const float w1 = __uint_as_float(PB[t].w);
        acc.x = fmaf(w0, VB[2*t].x, acc.x); acc.x = fmaf(w1, VB[2*t+1].x, acc.x);
        acc.y = fmaf(w0, VB[2*t].y, acc.y); acc.y = fmaf(w1, VB[2*t+1].y, acc.y);
        acc.z = fmaf(w0, VB[2*t].z, acc.z); acc.z = fmaf(w1, VB[2*t+1].z, acc.z);
        acc.w = fmaf(w0, VB[2*t].w, acc.w); acc.w = fmaf(w1, VB[2*t+1].w, acc.w);
    }

    // consume batch A2 (level 0)
    #pragma unroll
    for (int t = 0; t < 4; ++t) {
        const float w0 = __uint_as_float(PA[t].y);
        const float w1 = __uint_as_float(PA[t].w);
        acc.x = fmaf(w0, VA[2*t].x, acc.x); acc.x = fmaf(w1, VA[2*t+1].x, acc.x);
        acc.y = fmaf(w0, VA[2*t].y, acc.y); acc.y = fmaf(w1, VA[2*t+1].y, acc.y);
        acc.z = fmaf(w0, VA[2*t].z, acc.z); acc.z = fmaf(w1, VA[2*t+1].z, acc.z);
        acc.w = fmaf(w0, VA[2*t].w, acc.w); acc.w = fmaf(w1, VA[2*t+1].w, acc.w);
    }

    if (alive) {
        float* o = out + (size_t)q * 256 + h * 32 + sub * 4;
        *(float4*)o = acc;
        *(float4*)(o + GKA_OUT_HALF) = acc;
    }
}

extern "C" void kernel_launch(void* const* d_in, const int* in_sizes, int n_in,
                              void* d_out, int out_size, void* d_ws, size_t ws_size,
                              hipStream_t stream) {
    const float* value = (const float*)d_in[0];
    const float* sloc  = (const float*)d_in[3];
    const float* awgt  = (const float*)d_in[4];
    float* out = (float*)d_out;

    // ceil(20000/64) = 313 query-chunks x 8 heads; blockIdx%8 == head.
    dim3 grid(313 * GKA_H);
    gka_kernel<<<grid, 512, 0, stream>>>(value, sloc, awgt, out);
}